// Round 4
// baseline (438.770 us; speedup 1.0000x reference)
//
#include <hip/hip_runtime.h>
#include <cmath>

#define TSIZE (1 << 19)   // hash table entries per level

typedef __bf16 bf16x8 __attribute__((ext_vector_type(8)));
typedef float  f32x4  __attribute__((ext_vector_type(4)));

struct Res16 { int r[16]; };

// float -> bf16 bits, round-to-nearest-even
static __device__ __forceinline__ short f2bf(float f) {
    union { float f; unsigned u; } v; v.f = f;
    unsigned r = v.u + 0x7FFFu + ((v.u >> 16) & 1u);
    return (short)(r >> 16);
}

// softplus(t) = max(t,0) + log1p(exp(-|t|))  (scale 100/0.01 folded by caller)
static __device__ __forceinline__ float spr(float t) {
    float e = __expf(-fabsf(t));
    return fmaxf(t, 0.0f) + __logf(1.0f + e);
}

// swizzled LDS offset: row m, col k, row stride `stride` (shorts).
static __device__ __forceinline__ int swz(int m, int k, int stride) {
    return m * stride + ((((k >> 3) ^ (m & 7)) << 3) | (k & 7));
}

static __device__ __forceinline__ bool bit(const unsigned mk[4], int k) {
    return (mk[k >> 5] >> (k & 31)) & 1u;
}

// Pack W0 [256,121] (x100, fold softplus beta) and W1 [256,256] into MFMA
// fragment order: ((kt*256 + n)*4 + q)*8 + j  holds  W[n][kt*32+q*8+j] (bf16).
// Block 0 additionally builds the live-input-column bitmask of W0.
__global__ __launch_bounds__(256) void pack_weights(
    const float* __restrict__ W0, const float* __restrict__ W1,
    short* __restrict__ B0p, short* __restrict__ B1p, unsigned* __restrict__ mask) {
    int tid = threadIdx.x;
    int i = blockIdx.x * 256 + tid;              // 0..65535
    int j = i & 7, q = (i >> 3) & 3, n = (i >> 5) & 255, kt = i >> 13;
    int k = kt * 32 + q * 8 + j;
    if (i < 32768) {                             // B0p: kt 0..3 (K=128, 121 used)
        B0p[i] = f2bf(k < 121 ? 100.0f * W0[n * 121 + k] : 0.0f);
    }
    B1p[i] = f2bf(W1[n * 256 + k]);              // B1p: kt 0..7 (K=256)

    if (blockIdx.x == 0) {
        __shared__ unsigned lm[4];
        if (tid < 4) lm[tid] = 0u;
        __syncthreads();
        unsigned acc[4] = {0u, 0u, 0u, 0u};
        for (int e = tid; e < 256 * 121; e += 256) {   // coalesced flat scan
            if (W0[e] != 0.0f) { int kc = e % 121; acc[kc >> 5] |= 1u << (kc & 31); }
        }
        #pragma unroll
        for (int wi = 0; wi < 4; ++wi) if (acc[wi]) atomicOr(&lm[wi], acc[wi]);
        __syncthreads();
        if (tid < 4) mask[tid] = lm[tid];
    }
}

// Persistent fused encode + 3-layer MLP. Grid = 512 blocks x 256 threads;
// each block loops over 16 point-tiles of 64. W1 fragments for kt0..3 live in
// VGPRs for the whole kernel; kt4..7 fragments are prefetched per tile before
// the kt0..3 MFMA burst (L2 latency hidden under MFMA). K-loops are pure
// LDS+MFMA — no per-kt VMEM waits. launch_bounds(256,2): 256-reg cap vs ~230
// needed (R3's (256,4) forced a 128-reg cap -> 330 MB of scratch spills).
__global__ __launch_bounds__(256, 2) void fused_mlp(
    const float* __restrict__ x, const float* __restrict__ table,
    const float* __restrict__ b0, const float* __restrict__ b1,
    const float* __restrict__ W2, const float* __restrict__ b2,
    const short* __restrict__ B0p, const short* __restrict__ B1p,
    const unsigned* __restrict__ mask,
    float* __restrict__ out, int npts, Res16 R)
{
    __shared__ short sA[64 * 128];   // input tile  [64 pts][K=128] bf16 (16 KB)
    __shared__ short sB[64 * 256];   // hidden0     [64 pts][K=256] bf16 (32 KB)
    __shared__ float sX[192];        // staged x for 64 points
    __shared__ float sC[768];        // 100*b0 | 100*b1 | 0.01*W2
    __shared__ float sP[256];        // layer-2 partials [point][wave]

    const int tid = threadIdx.x;
    const int lane = tid & 63, w = tid >> 6;    // wave w: hidden cols nb..nb+63
    const int quad = lane >> 4, l15 = lane & 15;
    const int nb = w * 64;

    unsigned mk[4];
    mk[0] = mask[0]; mk[1] = mask[1]; mk[2] = mask[2]; mk[3] = mask[3];
    bool ktl[4];
    ktl[0] = mk[0] != 0u;
    ktl[1] = mk[1] != 0u;
    ktl[2] = mk[2] != 0u;
    ktl[3] = (mk[3] & 0x01FFFFFFu) != 0u;
    const float b2r = b2[0];

    // ---- once: stage constants, zero sA (dead cols must stay 0) ------------
    sC[tid]       = 100.0f * b0[tid];
    sC[256 + tid] = 100.0f * b1[tid];
    sC[512 + tid] = 0.01f  * W2[tid];
    {
        int4 z; z.x = 0; z.y = 0; z.z = 0; z.w = 0;
        int4* p = (int4*)sA;
        #pragma unroll
        for (int i = 0; i < 4; ++i) p[tid + i * 256] = z;
    }

    // ---- once: hold W1 fragments for kt 0..3 in registers ------------------
    bf16x8 w1h[4][4];
    #pragma unroll
    for (int kt = 0; kt < 4; ++kt)
        #pragma unroll
        for (int ni = 0; ni < 4; ++ni)
            w1h[kt][ni] = *(const bf16x8*)&B1p[((kt * 256 + nb + ni * 16 + l15) * 4 + quad) * 8];

    const int ntiles = (npts + 63) / 64;
    const f32x4 zero = {0.f, 0.f, 0.f, 0.f};

    for (int tile = blockIdx.x; tile < ntiles; tile += gridDim.x) {

        // ---- stage x (coalesced) ------------------------------------------
        if (tid < 192) {
            int xi = tile * 192 + tid;
            sX[tid] = (xi < npts * 3) ? x[xi] : 0.0f;
        }
        __syncthreads();   // (a) sX ready

        // ---- Phase E: encode live input cols of 64 points into sA ---------
        {
            const int m = tid >> 2;          // local point 0..63
            const int g = tid & 3;           // 4 workers per point
            float xv[3];
            xv[0] = sX[m * 3 + 0]; xv[1] = sX[m * 3 + 1]; xv[2] = sX[m * 3 + 2];

            if (g == 0) {                    // raw coords, cols 0..2
                #pragma unroll
                for (int d = 0; d < 3; ++d) sA[swz(m, d, 128)] = f2bf(xv[d]);
            }
            // positional embed: sin cols 3+3f+d, cos cols 30+3f+d
            for (int f = g; f < 9; f += 4) {
                float fs = (float)(1 << f);
                #pragma unroll
                for (int d = 0; d < 3; ++d) {
                    bool ns = bit(mk, 3 + f * 3 + d);
                    bool nc = bit(mk, 30 + f * 3 + d);
                    if (ns | nc) {
                        float v = xv[d] * fs;
                        if (ns) sA[swz(m, 3 + f * 3 + d, 128)]  = f2bf(__builtin_sinf(v));
                        if (nc) sA[swz(m, 30 + f * 3 + d, 128)] = f2bf(__builtin_cosf(v));
                    }
                }
            }
            // hash-grid levels g*4..g*4+3 -> cols 57 + 4*lvl (skipped when dead)
            #pragma unroll
            for (int li = 0; li < 4; ++li) {
                int i0 = R.r[li], i1 = R.r[4 + li], i2 = R.r[8 + li], i3 = R.r[12 + li];
                int res = (g == 0) ? i0 : (g == 1) ? i1 : (g == 2) ? i2 : i3;
                int lvl = g * 4 + li;
                int kb = 57 + lvl * 4;
                bool need = bit(mk, kb) | bit(mk, kb + 1) | bit(mk, kb + 2) | bit(mk, kb + 3);
                if (!need) continue;
                int rp1 = res + 1;
                bool dense = (rp1 <= 80);    // (res+1)^3 <= 2^19
                float fx[3]; int pi[3];
                #pragma unroll
                for (int d = 0; d < 3; ++d) {
                    float p  = xv[d] * (float)res;
                    float pf = floorf(p);
                    fx[d] = p - pf;
                    int qv = (int)pf;
                    pi[d] = min(max(qv, 0), res - 1);
                }
                float a0 = 0.f, a1 = 0.f, a2 = 0.f, a3 = 0.f;
                const float* tb = table + (size_t)lvl * (TSIZE * 4);
                #pragma unroll
                for (int c = 0; c < 8; ++c) {
                    int cx = pi[0] + (c & 1);
                    int cy = pi[1] + ((c >> 1) & 1);
                    int cz = pi[2] + ((c >> 2) & 1);
                    unsigned di = (unsigned)(cx + cy * rp1 + cz * rp1 * rp1);
                    unsigned hi = ((unsigned)cx ^ ((unsigned)cy * 2654435761u)
                                                ^ ((unsigned)cz * 805459861u)) & (unsigned)(TSIZE - 1);
                    unsigned idx = dense ? di : hi;
                    float4 t = *(const float4*)(tb + (size_t)idx * 4);
                    float wgt = ((c & 1) ? fx[0] : 1.0f - fx[0])
                              * ((c & 2) ? fx[1] : 1.0f - fx[1])
                              * ((c & 4) ? fx[2] : 1.0f - fx[2]);
                    a0 += wgt * t.x; a1 += wgt * t.y; a2 += wgt * t.z; a3 += wgt * t.w;
                }
                sA[swz(m, kb + 0, 128)] = f2bf(a0);
                sA[swz(m, kb + 1, 128)] = f2bf(a1);
                sA[swz(m, kb + 2, 128)] = f2bf(a2);
                sA[swz(m, kb + 3, 128)] = f2bf(a3);
            }
        }

        __syncthreads();   // (b) sA ready

        f32x4 acc[4][4];   // [ni (hidden frag)][mj (point frag)]
        #pragma unroll
        for (int ni = 0; ni < 4; ++ni)
            #pragma unroll
            for (int mj = 0; mj < 4; ++mj) acc[ni][mj] = zero;

        // GEMM0': D[n][m] = sum_k W0'[n][k] X[m][k]  (live K-tiles only)
        #pragma unroll
        for (int kt = 0; kt < 4; ++kt) {
            if (!ktl[kt]) continue;
            bf16x8 afr[4], bfr[4];
            #pragma unroll
            for (int ni = 0; ni < 4; ++ni)
                afr[ni] = *(const bf16x8*)&B0p[((kt * 256 + nb + ni * 16 + l15) * 4 + quad) * 8];
            #pragma unroll
            for (int mj = 0; mj < 4; ++mj) {
                int m = mj * 16 + l15, c = kt * 4 + quad;
                bfr[mj] = *(const bf16x8*)&sA[m * 128 + ((c ^ (m & 7)) << 3)];
            }
            #pragma unroll
            for (int ni = 0; ni < 4; ++ni)
                #pragma unroll
                for (int mj = 0; mj < 4; ++mj)
                    acc[ni][mj] = __builtin_amdgcn_mfma_f32_16x16x32_bf16(afr[ni], bfr[mj], acc[ni][mj], 0, 0, 0);
        }

        // epilogue0: H0' = softplus(acc + 100*b0), packed b64 stores
        #pragma unroll
        for (int ni = 0; ni < 4; ++ni) {
            float4 b0v = *(const float4*)&sC[nb + ni * 16 + quad * 4];
            int c = (nb + ni * 16 + quad * 4) >> 3;
            #pragma unroll
            for (int mj = 0; mj < 4; ++mj) {
                int m = mj * 16 + l15;
                short4 h;
                h.x = f2bf(spr(acc[ni][mj][0] + b0v.x));
                h.y = f2bf(spr(acc[ni][mj][1] + b0v.y));
                h.z = f2bf(spr(acc[ni][mj][2] + b0v.z));
                h.w = f2bf(spr(acc[ni][mj][3] + b0v.w));
                *(short4*)&sB[m * 256 + (((c ^ (m & 7)) << 3) | ((quad & 1) << 2))] = h;
            }
        }

        __syncthreads();   // (c) sB (H0') ready

        // prefetch streamed W1 fragments (kt 4..7) — consumed after kt0..3,
        // so ~1200 cyc of held-weight MFMA hides the L2 latency.
        bf16x8 w1s[4][4];
        #pragma unroll
        for (int kt = 4; kt < 8; ++kt)
            #pragma unroll
            for (int ni = 0; ni < 4; ++ni)
                w1s[kt - 4][ni] = *(const bf16x8*)&B1p[((kt * 256 + nb + ni * 16 + l15) * 4 + quad) * 8];

        #pragma unroll
        for (int ni = 0; ni < 4; ++ni)
            #pragma unroll
            for (int mj = 0; mj < 4; ++mj) acc[ni][mj] = zero;

        // GEMM1' kt 0..3: held weights, pure LDS+MFMA
        #pragma unroll
        for (int kt = 0; kt < 4; ++kt) {
            bf16x8 bfr[4];
            #pragma unroll
            for (int mj = 0; mj < 4; ++mj) {
                int m = mj * 16 + l15, c = kt * 4 + quad;
                bfr[mj] = *(const bf16x8*)&sB[m * 256 + ((c ^ (m & 7)) << 3)];
            }
            #pragma unroll
            for (int ni = 0; ni < 4; ++ni)
                #pragma unroll
                for (int mj = 0; mj < 4; ++mj)
                    acc[ni][mj] = __builtin_amdgcn_mfma_f32_16x16x32_bf16(w1h[kt][ni], bfr[mj], acc[ni][mj], 0, 0, 0);
        }
        // GEMM1' kt 4..7: prefetched weights
        #pragma unroll
        for (int kt = 4; kt < 8; ++kt) {
            bf16x8 bfr[4];
            #pragma unroll
            for (int mj = 0; mj < 4; ++mj) {
                int m = mj * 16 + l15, c = kt * 4 + quad;
                bfr[mj] = *(const bf16x8*)&sB[m * 256 + ((c ^ (m & 7)) << 3)];
            }
            #pragma unroll
            for (int ni = 0; ni < 4; ++ni)
                #pragma unroll
                for (int mj = 0; mj < 4; ++mj)
                    acc[ni][mj] = __builtin_amdgcn_mfma_f32_16x16x32_bf16(w1s[kt - 4][ni], bfr[mj], acc[ni][mj], 0, 0, 0);
        }

        // epilogue1 fused with layer 2: out = softplus(.)*0.01W2 summed over n
        #pragma unroll
        for (int mj = 0; mj < 4; ++mj) {
            float p = 0.0f;
            #pragma unroll
            for (int ni = 0; ni < 4; ++ni) {
                float4 b1v = *(const float4*)&sC[256 + nb + ni * 16 + quad * 4];
                float4 w2v = *(const float4*)&sC[512 + nb + ni * 16 + quad * 4];
                p += spr(acc[ni][mj][0] + b1v.x) * w2v.x;
                p += spr(acc[ni][mj][1] + b1v.y) * w2v.y;
                p += spr(acc[ni][mj][2] + b1v.z) * w2v.z;
                p += spr(acc[ni][mj][3] + b1v.w) * w2v.w;
            }
            p += __shfl_xor(p, 16);   // sum over quads (same l15)
            p += __shfl_xor(p, 32);
            if (quad == 0) sP[(mj * 16 + l15) * 4 + w] = p;
        }

        __syncthreads();   // (d) sP ready

        if (tid < 64) {
            float s = sP[tid * 4 + 0] + sP[tid * 4 + 1] + sP[tid * 4 + 2] + sP[tid * 4 + 3] + b2r;
            int pt = tile * 64 + tid;
            if (pt < npts) out[pt] = s;
        }
        __syncthreads();   // (a') protect sX/sP reuse next tile
    }
}

extern "C" void kernel_launch(void* const* d_in, const int* in_sizes, int n_in,
                              void* d_out, int out_size, void* d_ws, size_t ws_size,
                              hipStream_t stream) {
    const float* x     = (const float*)d_in[0];
    const float* table = (const float*)d_in[1];
    const float* W0    = (const float*)d_in[2];
    const float* b0    = (const float*)d_in[3];
    const float* W1    = (const float*)d_in[4];
    const float* b1    = (const float*)d_in[5];
    const float* W2    = (const float*)d_in[6];
    const float* b2    = (const float*)d_in[7];
    float* out = (float*)d_out;
    int npts = in_sizes[0] / 3;

    // ws layout: B0p 32768 bf16 | B1p 65536 bf16 | mask 4 u32
    short* B0p = (short*)d_ws;
    short* B1p = B0p + 32768;
    unsigned* mask = (unsigned*)(B1p + 65536);

    // RES table: must match Python bit-for-bit -> identical libm expression.
    Res16 R;
    double s = ::pow(2.0, ::log2(2048.0 / 16.0) / 15.0);
    for (int l = 0; l < 16; ++l) R.r[l] = (int)::ceil(16.0 * ::pow(s, (double)l));

    hipLaunchKernelGGL(pack_weights, dim3(256), dim3(256), 0, stream, W0, W1, B0p, B1p, mask);
    hipLaunchKernelGGL(fused_mlp, dim3(512), dim3(256), 0, stream,
                       x, table, b0, b1, W2, b2, B0p, B1p, mask, out, npts, R);
}

// Round 5
// 316.349 us; speedup vs baseline: 1.3870x; 1.3870x over previous
//
#include <hip/hip_runtime.h>
#include <cmath>

#define TSIZE (1 << 19)   // hash table entries per level

typedef __bf16 bf16x8 __attribute__((ext_vector_type(8)));
typedef float  f32x4  __attribute__((ext_vector_type(4)));
typedef short  s16x8  __attribute__((ext_vector_type(8)));

struct Res16 { int r[16]; };

#define S0K 144.269504088896340f   // 100/ln2
#define SW2 0.00693147180559945f   // ln2/100

// float -> bf16 bits, round-to-nearest-even
static __device__ __forceinline__ short f2bf(float f) {
    union { float f; unsigned u; } v; v.f = f;
    unsigned r = v.u + 0x7FFFu + ((v.u >> 16) & 1u);
    return (short)(r >> 16);
}

// base-2 softplus core: spr2(t') = max(t',0) + log2(1 + 2^-|t'|)
// where t' = 100*z/ln2.  softplus100(z) = (ln2/100) * spr2(t').
static __device__ __forceinline__ float spr2(float t) {
    float e = __builtin_amdgcn_exp2f(-fabsf(t));
    return fmaxf(t, 0.0f) + __builtin_amdgcn_logf(1.0f + e);
}

// swizzled LDS offset: row m, col k, row stride `stride` (shorts).
static __device__ __forceinline__ int swz(int m, int k, int stride) {
    return m * stride + ((((k >> 3) ^ (m & 7)) << 3) | (k & 7));
}

static __device__ __forceinline__ bool bit(const unsigned mk[4], int k) {
    return (mk[k >> 5] >> (k & 31)) & 1u;
}

static __device__ __forceinline__ bool fastcase(const unsigned mk[4]) {
    return (((mk[0] & ~7u) | mk[1] | mk[2] | (mk[3] & 0x01FFFFFFu)) == 0u);
}

// Pack W0 [256,121] (x 100/ln2) and W1 [256,256] into MFMA fragment order:
// ((kt*256 + n)*4 + q)*8 + j  holds  W[n][kt*32+q*8+j] (bf16).
// Block 0: live-column bitmask of W0. Block 1: Wc const pack
// {W0x',W0y',W0z',b0',b1',W2'} (fp32, scales folded).
__global__ __launch_bounds__(256) void pack_weights(
    const float* __restrict__ W0, const float* __restrict__ W1,
    const float* __restrict__ b0, const float* __restrict__ b1,
    const float* __restrict__ W2,
    short* __restrict__ B0p, short* __restrict__ B1p,
    unsigned* __restrict__ mask, float* __restrict__ Wc) {
    int tid = threadIdx.x;
    int i = blockIdx.x * 256 + tid;              // 0..65535
    int j = i & 7, q = (i >> 3) & 3, n = (i >> 5) & 255, kt = i >> 13;
    int k = kt * 32 + q * 8 + j;
    if (i < 32768) {                             // B0p: kt 0..3 (K=128, 121 used)
        B0p[i] = f2bf(k < 121 ? S0K * W0[n * 121 + k] : 0.0f);
    }
    B1p[i] = f2bf(W1[n * 256 + k]);              // B1p: kt 0..7 (unchanged scale)

    if (blockIdx.x == 0) {
        __shared__ unsigned lm[4];
        if (tid < 4) lm[tid] = 0u;
        __syncthreads();
        unsigned acc[4] = {0u, 0u, 0u, 0u};
        for (int e = tid; e < 256 * 121; e += 256) {   // coalesced flat scan
            if (W0[e] != 0.0f) { int kc = e % 121; acc[kc >> 5] |= 1u << (kc & 31); }
        }
        #pragma unroll
        for (int wi = 0; wi < 4; ++wi) if (acc[wi]) atomicOr(&lm[wi], acc[wi]);
        __syncthreads();
        if (tid < 4) mask[tid] = lm[tid];
    }
    if (blockIdx.x == 1) {
        Wc[tid]        = S0K * W0[tid * 121 + 0];
        Wc[256 + tid]  = S0K * W0[tid * 121 + 1];
        Wc[512 + tid]  = S0K * W0[tid * 121 + 2];
        Wc[768 + tid]  = S0K * b0[tid];
        Wc[1024 + tid] = S0K * b1[tid];
        Wc[1280 + tid] = SW2 * W2[tid];
    }
}

// FAST kernel: runs only when live W0 cols are a subset of {x,y,z}.
// Layer 0 = rank-3 affine (pure fp32 VALU), no encode/GEMM0/sA/mask loops,
// 3 barriers/tile, lean registers -> (256,3): 3 waves/SIMD.
__global__ __launch_bounds__(256, 3) void fused_fast(
    const float* __restrict__ x,
    const short* __restrict__ B1p, const unsigned* __restrict__ mask,
    const float* __restrict__ Wc, const float* __restrict__ b2,
    float* __restrict__ out, int npts)
{
    unsigned mk[4];
    mk[0] = mask[0]; mk[1] = mask[1]; mk[2] = mask[2]; mk[3] = mask[3];
    if (!fastcase(mk)) return;   // general kernel owns this case

    __shared__ short sB[64 * 256];   // H0' tile [64 pts][256] bf16, swizzled (32 KB)
    __shared__ float sC[1536];       // W0x'|W0y'|W0z'|b0'|b1'|W2'  (6 KB)
    __shared__ float sX[192];
    __shared__ float sP[256];

    const int tid = threadIdx.x;
    const int blk = blockIdx.x;

    // stage consts + x (coalesced)
    #pragma unroll
    for (int j = 0; j < 6; ++j) sC[j * 256 + tid] = Wc[j * 256 + tid];
    if (tid < 192) {
        int xi = blk * 192 + tid;
        sX[tid] = (xi < npts * 3) ? x[xi] : 0.0f;
    }
    __syncthreads();   // (A)

    // ---- layer 0: H0'[m][n] = spr2(x.w0 + b0'), thread = (point m, seg) ----
    {
        const int m = tid & 63;          // point = lane
        const int seg = tid >> 6;        // hidden quarter (wave-uniform)
        float x0 = sX[m * 3 + 0], x1 = sX[m * 3 + 1], x2 = sX[m * 3 + 2];
        #pragma unroll
        for (int g8 = 0; g8 < 8; ++g8) {
            int n0 = seg * 64 + g8 * 8;
            s16x8 hp;
            #pragma unroll
            for (int jj = 0; jj < 8; ++jj) {
                int n = n0 + jj;
                float t = fmaf(x0, sC[n], fmaf(x1, sC[256 + n],
                              fmaf(x2, sC[512 + n], sC[768 + n])));
                hp[jj] = f2bf(spr2(t));
            }
            int c = n0 >> 3;
            *(s16x8*)&sB[m * 256 + ((c ^ (m & 7)) << 3)] = hp;   // ds_write_b128
        }
    }

    __syncthreads();   // (B) sB ready

    const int lane = tid & 63, w = tid >> 6;
    const int quad = lane >> 4, l15 = lane & 15;
    const int nb = w * 64;

    const f32x4 zero = {0.f, 0.f, 0.f, 0.f};
    f32x4 acc[4][4];   // [ni (hidden-1 frag)][mj (point frag)]
    #pragma unroll
    for (int ni = 0; ni < 4; ++ni)
        #pragma unroll
        for (int mj = 0; mj < 4; ++mj) acc[ni][mj] = zero;

    // GEMM1': D[n'][m] = sum_k W1[n'][k] H0'[m][k]   (K = 256)
    #pragma unroll
    for (int kt = 0; kt < 8; ++kt) {
        bf16x8 afr[4], bfr[4];
        #pragma unroll
        for (int ni = 0; ni < 4; ++ni)
            afr[ni] = *(const bf16x8*)&B1p[((kt * 256 + nb + ni * 16 + l15) * 4 + quad) * 8];
        #pragma unroll
        for (int mj = 0; mj < 4; ++mj) {
            int m = mj * 16 + l15, c = kt * 4 + quad;
            bfr[mj] = *(const bf16x8*)&sB[m * 256 + ((c ^ (m & 7)) << 3)];
        }
        #pragma unroll
        for (int ni = 0; ni < 4; ++ni)
            #pragma unroll
            for (int mj = 0; mj < 4; ++mj)
                acc[ni][mj] = __builtin_amdgcn_mfma_f32_16x16x32_bf16(afr[ni], bfr[mj], acc[ni][mj], 0, 0, 0);
    }

    // epilogue: out = sum_n' spr2(acc + b1') * W2' + b2
    #pragma unroll
    for (int mj = 0; mj < 4; ++mj) {
        float p = 0.0f;
        #pragma unroll
        for (int ni = 0; ni < 4; ++ni) {
            float4 b1v = *(const float4*)&sC[1024 + nb + ni * 16 + quad * 4];
            float4 w2v = *(const float4*)&sC[1280 + nb + ni * 16 + quad * 4];
            p += spr2(acc[ni][mj][0] + b1v.x) * w2v.x;
            p += spr2(acc[ni][mj][1] + b1v.y) * w2v.y;
            p += spr2(acc[ni][mj][2] + b1v.z) * w2v.z;
            p += spr2(acc[ni][mj][3] + b1v.w) * w2v.w;
        }
        p += __shfl_xor(p, 16);
        p += __shfl_xor(p, 32);
        if (quad == 0) sP[(mj * 16 + l15) * 4 + w] = p;
    }

    __syncthreads();   // (C)

    if (tid < 64) {
        float s = sP[tid * 4 + 0] + sP[tid * 4 + 1] + sP[tid * 4 + 2] + sP[tid * 4 + 3] + b2[0];
        int pt = blk * 64 + tid;
        if (pt < npts) out[pt] = s;
    }
}

// GENERAL kernel (dormant for this data): full encode + GEMM0 + GEMM1,
// persistent 512 blocks. Early-exits when the fast case holds.
__global__ __launch_bounds__(256, 2) void fused_general(
    const float* __restrict__ x, const float* __restrict__ table,
    const float* __restrict__ Wc, const float* __restrict__ b2,
    const short* __restrict__ B0p, const short* __restrict__ B1p,
    const unsigned* __restrict__ mask,
    float* __restrict__ out, int npts, Res16 R)
{
    unsigned mk[4];
    mk[0] = mask[0]; mk[1] = mask[1]; mk[2] = mask[2]; mk[3] = mask[3];
    if (fastcase(mk)) return;    // fast kernel owns this case

    __shared__ short sA[64 * 128];
    __shared__ short sB[64 * 256];
    __shared__ float sX[192];
    __shared__ float sC[768];        // b0' | b1' | W2'
    __shared__ float sP[256];

    const int tid = threadIdx.x;
    const int lane = tid & 63, w = tid >> 6;
    const int quad = lane >> 4, l15 = lane & 15;
    const int nb = w * 64;

    bool ktl[4];
    ktl[0] = mk[0] != 0u;
    ktl[1] = mk[1] != 0u;
    ktl[2] = mk[2] != 0u;
    ktl[3] = (mk[3] & 0x01FFFFFFu) != 0u;
    const float b2r = b2[0];

    sC[tid]       = Wc[768 + tid];
    sC[256 + tid] = Wc[1024 + tid];
    sC[512 + tid] = Wc[1280 + tid];
    {
        int4 z; z.x = 0; z.y = 0; z.z = 0; z.w = 0;
        int4* p = (int4*)sA;
        #pragma unroll
        for (int i = 0; i < 4; ++i) p[tid + i * 256] = z;
    }

    const int ntiles = (npts + 63) / 64;
    const f32x4 zero = {0.f, 0.f, 0.f, 0.f};

    for (int tile = blockIdx.x; tile < ntiles; tile += gridDim.x) {
        if (tid < 192) {
            int xi = tile * 192 + tid;
            sX[tid] = (xi < npts * 3) ? x[xi] : 0.0f;
        }
        __syncthreads();

        {
            const int m = tid >> 2;
            const int g = tid & 3;
            float xv[3];
            xv[0] = sX[m * 3 + 0]; xv[1] = sX[m * 3 + 1]; xv[2] = sX[m * 3 + 2];

            if (g == 0) {
                #pragma unroll
                for (int d = 0; d < 3; ++d) sA[swz(m, d, 128)] = f2bf(xv[d]);
            }
            for (int f = g; f < 9; f += 4) {
                float fs = (float)(1 << f);
                #pragma unroll
                for (int d = 0; d < 3; ++d) {
                    bool ns = bit(mk, 3 + f * 3 + d);
                    bool nc = bit(mk, 30 + f * 3 + d);
                    if (ns | nc) {
                        float v = xv[d] * fs;
                        if (ns) sA[swz(m, 3 + f * 3 + d, 128)]  = f2bf(__builtin_sinf(v));
                        if (nc) sA[swz(m, 30 + f * 3 + d, 128)] = f2bf(__builtin_cosf(v));
                    }
                }
            }
            #pragma unroll
            for (int li = 0; li < 4; ++li) {
                int i0 = R.r[li], i1 = R.r[4 + li], i2 = R.r[8 + li], i3 = R.r[12 + li];
                int res = (g == 0) ? i0 : (g == 1) ? i1 : (g == 2) ? i2 : i3;
                int lvl = g * 4 + li;
                int kb = 57 + lvl * 4;
                bool need = bit(mk, kb) | bit(mk, kb + 1) | bit(mk, kb + 2) | bit(mk, kb + 3);
                if (!need) continue;
                int rp1 = res + 1;
                bool dense = (rp1 <= 80);
                float fx[3]; int pi[3];
                #pragma unroll
                for (int d = 0; d < 3; ++d) {
                    float p  = xv[d] * (float)res;
                    float pf = floorf(p);
                    fx[d] = p - pf;
                    int qv = (int)pf;
                    pi[d] = min(max(qv, 0), res - 1);
                }
                float a0 = 0.f, a1 = 0.f, a2 = 0.f, a3 = 0.f;
                const float* tb = table + (size_t)lvl * (TSIZE * 4);
                #pragma unroll
                for (int c = 0; c < 8; ++c) {
                    int cx = pi[0] + (c & 1);
                    int cy = pi[1] + ((c >> 1) & 1);
                    int cz = pi[2] + ((c >> 2) & 1);
                    unsigned di = (unsigned)(cx + cy * rp1 + cz * rp1 * rp1);
                    unsigned hi = ((unsigned)cx ^ ((unsigned)cy * 2654435761u)
                                                ^ ((unsigned)cz * 805459861u)) & (unsigned)(TSIZE - 1);
                    unsigned idx = dense ? di : hi;
                    float4 t = *(const float4*)(tb + (size_t)idx * 4);
                    float wgt = ((c & 1) ? fx[0] : 1.0f - fx[0])
                              * ((c & 2) ? fx[1] : 1.0f - fx[1])
                              * ((c & 4) ? fx[2] : 1.0f - fx[2]);
                    a0 += wgt * t.x; a1 += wgt * t.y; a2 += wgt * t.z; a3 += wgt * t.w;
                }
                sA[swz(m, kb + 0, 128)] = f2bf(a0);
                sA[swz(m, kb + 1, 128)] = f2bf(a1);
                sA[swz(m, kb + 2, 128)] = f2bf(a2);
                sA[swz(m, kb + 3, 128)] = f2bf(a3);
            }
        }

        __syncthreads();

        f32x4 acc[4][4];
        #pragma unroll
        for (int ni = 0; ni < 4; ++ni)
            #pragma unroll
            for (int mj = 0; mj < 4; ++mj) acc[ni][mj] = zero;

        #pragma unroll
        for (int kt = 0; kt < 4; ++kt) {
            if (!ktl[kt]) continue;
            bf16x8 afr[4], bfr[4];
            #pragma unroll
            for (int ni = 0; ni < 4; ++ni)
                afr[ni] = *(const bf16x8*)&B0p[((kt * 256 + nb + ni * 16 + l15) * 4 + quad) * 8];
            #pragma unroll
            for (int mj = 0; mj < 4; ++mj) {
                int m = mj * 16 + l15, c = kt * 4 + quad;
                bfr[mj] = *(const bf16x8*)&sA[m * 128 + ((c ^ (m & 7)) << 3)];
            }
            #pragma unroll
            for (int ni = 0; ni < 4; ++ni)
                #pragma unroll
                for (int mj = 0; mj < 4; ++mj)
                    acc[ni][mj] = __builtin_amdgcn_mfma_f32_16x16x32_bf16(afr[ni], bfr[mj], acc[ni][mj], 0, 0, 0);
        }

        #pragma unroll
        for (int ni = 0; ni < 4; ++ni) {
            float4 b0v = *(const float4*)&sC[nb + ni * 16 + quad * 4];
            int c = (nb + ni * 16 + quad * 4) >> 3;
            #pragma unroll
            for (int mj = 0; mj < 4; ++mj) {
                int m = mj * 16 + l15;
                short4 h;
                h.x = f2bf(spr2(acc[ni][mj][0] + b0v.x));
                h.y = f2bf(spr2(acc[ni][mj][1] + b0v.y));
                h.z = f2bf(spr2(acc[ni][mj][2] + b0v.z));
                h.w = f2bf(spr2(acc[ni][mj][3] + b0v.w));
                *(short4*)&sB[m * 256 + (((c ^ (m & 7)) << 3) | ((quad & 1) << 2))] = h;
            }
        }

        __syncthreads();

        #pragma unroll
        for (int ni = 0; ni < 4; ++ni)
            #pragma unroll
            for (int mj = 0; mj < 4; ++mj) acc[ni][mj] = zero;

        #pragma unroll
        for (int kt = 0; kt < 8; ++kt) {
            bf16x8 afr[4], bfr[4];
            #pragma unroll
            for (int ni = 0; ni < 4; ++ni)
                afr[ni] = *(const bf16x8*)&B1p[((kt * 256 + nb + ni * 16 + l15) * 4 + quad) * 8];
            #pragma unroll
            for (int mj = 0; mj < 4; ++mj) {
                int m = mj * 16 + l15, c = kt * 4 + quad;
                bfr[mj] = *(const bf16x8*)&sB[m * 256 + ((c ^ (m & 7)) << 3)];
            }
            #pragma unroll
            for (int ni = 0; ni < 4; ++ni)
                #pragma unroll
                for (int mj = 0; mj < 4; ++mj)
                    acc[ni][mj] = __builtin_amdgcn_mfma_f32_16x16x32_bf16(afr[ni], bfr[mj], acc[ni][mj], 0, 0, 0);
        }

        #pragma unroll
        for (int mj = 0; mj < 4; ++mj) {
            float p = 0.0f;
            #pragma unroll
            for (int ni = 0; ni < 4; ++ni) {
                float4 b1v = *(const float4*)&sC[256 + nb + ni * 16 + quad * 4];
                float4 w2v = *(const float4*)&sC[512 + nb + ni * 16 + quad * 4];
                p += spr2(acc[ni][mj][0] + b1v.x) * w2v.x;
                p += spr2(acc[ni][mj][1] + b1v.y) * w2v.y;
                p += spr2(acc[ni][mj][2] + b1v.z) * w2v.z;
                p += spr2(acc[ni][mj][3] + b1v.w) * w2v.w;
            }
            p += __shfl_xor(p, 16);
            p += __shfl_xor(p, 32);
            if (quad == 0) sP[(mj * 16 + l15) * 4 + w] = p;
        }

        __syncthreads();

        if (tid < 64) {
            float s = sP[tid * 4 + 0] + sP[tid * 4 + 1] + sP[tid * 4 + 2] + sP[tid * 4 + 3] + b2r;
            int pt = tile * 64 + tid;
            if (pt < npts) out[pt] = s;
        }
        __syncthreads();
    }
}

extern "C" void kernel_launch(void* const* d_in, const int* in_sizes, int n_in,
                              void* d_out, int out_size, void* d_ws, size_t ws_size,
                              hipStream_t stream) {
    const float* x     = (const float*)d_in[0];
    const float* table = (const float*)d_in[1];
    const float* W0    = (const float*)d_in[2];
    const float* b0    = (const float*)d_in[3];
    const float* W1    = (const float*)d_in[4];
    const float* b1    = (const float*)d_in[5];
    const float* W2    = (const float*)d_in[6];
    const float* b2    = (const float*)d_in[7];
    float* out = (float*)d_out;
    int npts = in_sizes[0] / 3;

    // ws: B0p 32768 sh | B1p 65536 sh | mask 8 u32 | Wc 1536 f32
    short* B0p = (short*)d_ws;
    short* B1p = B0p + 32768;
    unsigned* mask = (unsigned*)(B1p + 65536);
    float* Wc = (float*)(mask + 8);

    // RES table: must match Python bit-for-bit -> identical libm expression.
    Res16 R;
    double s = ::pow(2.0, ::log2(2048.0 / 16.0) / 15.0);
    for (int l = 0; l < 16; ++l) R.r[l] = (int)::ceil(16.0 * ::pow(s, (double)l));

    hipLaunchKernelGGL(pack_weights, dim3(256), dim3(256), 0, stream,
                       W0, W1, b0, b1, W2, B0p, B1p, mask, Wc);
    hipLaunchKernelGGL(fused_general, dim3(512), dim3(256), 0, stream,
                       x, table, Wc, b2, B0p, B1p, mask, out, npts, R);
    int nblk = (npts + 63) / 64;
    hipLaunchKernelGGL(fused_fast, dim3(nblk), dim3(256), 0, stream,
                       x, B1p, mask, Wc, b2, out, npts);
}